// Round 7
// baseline (43005.545 us; speedup 1.0000x reference)
//
#include <hip/hip_runtime.h>
#include <math.h>

#define BSZ   384
#define BM1   383
#define DIM   256
#define NZTOT 768
#define NBLK  192
#define RPB   2
#define TPB   384
#define NITER 100
#define RINGD 8
#define NAGPR 256              // KK rows 0..255 resident in AGPRs
#define NVREG 128              // KK rows 256..383 resident in VGPRs

// ---- ws layout (float offsets) ----
#define OFF_Z    0          // 768*256
#define OFF_NRM  196608     // 768
#define OFF_K    197376     // 384*768
#define OFF_KP   492288     // 384*384 packed KK
#define OFF_A    639744     // 384*383 final alpha
#define OFF_NUM  786816     // NITER (pad 128)
#define OFF_DEN  786944
#define OFF_ARR  787072
#define OFF_LOSS 787200     // 2 doubles

__global__ void init_kernel(float* num, float* den, int* arr, double* lossAcc) {
    int t = threadIdx.x;
    if (t < NITER) { num[t] = 0.f; den[t] = 0.f; arr[t] = 0; }
    if (t < 2) lossAcc[t] = 0.0;
}

__global__ void __launch_bounds__(64)
norm_kernel(const float* __restrict__ xis, const float* __restrict__ xjs,
            float* __restrict__ Z, float* __restrict__ nrm2) {
    const int row  = blockIdx.x;
    const int lane = threadIdx.x;
    const float* src = (row < BSZ) ? (xis + (size_t)row * DIM)
                                   : (xjs + (size_t)(row - BSZ) * DIM);
    float4 x = reinterpret_cast<const float4*>(src)[lane];
    float s = x.x*x.x + x.y*x.y + x.z*x.z + x.w*x.w;
    for (int m = 32; m; m >>= 1) s += __shfl_xor(s, m, 64);
    float nrm = sqrtf(s);
    float4 z;
    z.x = x.x / nrm; z.y = x.y / nrm; z.z = x.z / nrm; z.w = x.w / nrm;
    reinterpret_cast<float4*>(Z + (size_t)row * DIM)[lane] = z;
    float s2 = z.x*z.x + z.y*z.y + z.z*z.z + z.w*z.w;
    for (int m = 32; m; m >>= 1) s2 += __shfl_xor(s2, m, 64);
    if (lane == 0) nrm2[row] = s2;
}

__global__ void __launch_bounds__(256)
k_kernel(const float* __restrict__ Z, const float* __restrict__ nrm2,
         float* __restrict__ Km, float* __restrict__ KKp) {
    const int i = blockIdx.x;
    const int j = blockIdx.y * 256 + threadIdx.x;
    __shared__ float zi[DIM];
    zi[threadIdx.x] = Z[(size_t)i * DIM + threadIdx.x];
    __syncthreads();
    const float4* zr = reinterpret_cast<const float4*>(Z + (size_t)j * DIM);
    float acc = 0.f;
    #pragma unroll 8
    for (int k = 0; k < DIM/4; ++k) {
        float4 v = zr[k];
        acc = fmaf(zi[4*k+0], v.x, acc);
        acc = fmaf(zi[4*k+1], v.y, acc);
        acc = fmaf(zi[4*k+2], v.z, acc);
        acc = fmaf(zi[4*k+3], v.w, acc);
    }
    float sq = nrm2[i] + nrm2[j] - 2.f * acc;
    sq = fmaxf(sq, 0.f);
    const float val = expf(-0.1f * sq);
    Km[(size_t)i * NZTOT + j] = val;
    if (j < BSZ) KKp[(size_t)i * BSZ + j] = val;
}

__global__ void __launch_bounds__(TPB, 1)
pgd_kernel(const float* __restrict__ Km, const float* __restrict__ KKp,
           const float* __restrict__ alpha_init,
           float* __restrict__ afin, float* num, float* den, int* arr) {
    const int g    = blockIdx.x;     // 0..191
    const int c    = threadIdx.x;    // column 0..383
    const int lane = c & 63;
    const int wv   = c >> 6;

    __shared__ float4 zrow4[RPB][98];         // 392 floats/row
    __shared__ float  rscr[6][8];
    __shared__ float  rscr2[6];
    __shared__ float  SD[8];                  // 0..1 S_r, 2..3 D_r, 4 den
    __shared__ unsigned long long scanm[2];

    // ---- per-row init (column indexing; diagonal thread c==b inert) ----
    float a[RPB], p[RPB], kb[RPB];
    int   bb[RPB]; bool vld[RPB];
    #pragma unroll
    for (int r = 0; r < RPB; ++r) {
        const int b = g * RPB + r;
        bb[r]  = b;
        vld[r] = (c != b);
        kb[r]  = Km[(size_t)b * NZTOT + c];
        float v = 0.f;
        if (vld[r]) {
            const int i = c - (c > b ? 1 : 0);
            v = alpha_init[(size_t)b * BM1 + i];
            v = fminf(fmaxf(v, 0.f), 1.f);
        }
        a[r] = v; p[r] = v;
    }
    float hist[RINGD][RPB];
    #pragma unroll
    for (int s = 0; s < RINGD; ++s)
        #pragma unroll
        for (int r = 0; r < RPB; ++r) hist[s][r] = a[r];

    // ---- prologue: K column c becomes fully register-resident (once) ----
    // rows 0..255 -> AGPRs a0..a255 (pinned via "a" asm constraints)
    float ka[NAGPR];
    #pragma unroll
    for (int j = 0; j < NAGPR; ++j) {
        const float v = KKp[(size_t)j * BSZ + c];
        asm volatile("v_accvgpr_write_b32 %0, %1" : "=a"(ka[j]) : "v"(v));
    }
    // rows 256..383 -> VGPRs
    float kk[NVREG];
    #pragma unroll
    for (int j = 0; j < NVREG; ++j) kk[j] = KKp[(size_t)(NAGPR + j) * BSZ + c];

    int stopT = -1;

    for (int t = 0; t < NITER; ++t) {
        // ---- phase 1: z build + S, D, den partials ----
        const float beta = (float)t / ((float)t + 3.0f);
        float z[RPB]; float vv[5]; float denp = 0.f;
        #pragma unroll
        for (int r = 0; r < RPB; ++r) {
            const float zr = a[r] + beta * (a[r] - p[r]);   // 0 on diagonal thread
            z[r] = zr;
            ((float*)&zrow4[r][0])[c] = zr;
            vv[r]     = zr;
            vv[2 + r] = kb[r] * zr;
            denp += a[r] * a[r];
        }
        vv[4] = denp;
        #pragma unroll
        for (int k = 0; k < 5; ++k) {
            float x = vv[k];
            x += __shfl_down(x, 32, 64); x += __shfl_down(x, 16, 64);
            x += __shfl_down(x,  8, 64); x += __shfl_down(x,  4, 64);
            x += __shfl_down(x,  2, 64); x += __shfl_down(x,  1, 64);
            if (lane == 0) rscr[wv][k] = x;
        }

        // ---- spin-free stop scan: thread tau checks iteration tau ----
        int ok = 0;
        if (c < NITER) {
            const int av = __hip_atomic_load(&arr[c], __ATOMIC_ACQUIRE, __HIP_MEMORY_SCOPE_AGENT);
            if (av == NBLK) {
                const float nn = __hip_atomic_load(&num[c], __ATOMIC_RELAXED, __HIP_MEMORY_SCOPE_AGENT);
                const float dd = __hip_atomic_load(&den[c], __ATOMIC_RELAXED, __HIP_MEMORY_SCOPE_AGENT);
                ok = (sqrtf(nn) / (sqrtf(dd) + 1e-8f) < 0.01f) ? 1 : 0;
            }
        }
        {
            const unsigned long long bm = __ballot(ok);
            if (lane == 0 && wv < 2) scanm[wv] = bm;
        }
        __syncthreads();   // B1
        {
            const unsigned long long m0 = scanm[0], m1 = scanm[1];
            const int st = m0 ? (__ffsll(m0) - 1) : (m1 ? 63 + __ffsll(m1) : -1);
            if (st >= 0) { stopT = st; break; }   // uniform across block
        }
        if (c < 5) {
            float s = 0.f;
            #pragma unroll
            for (int w = 0; w < 6; ++w) s += rscr[w][c];
            SD[c] = s;
        }

        // ---- phase 2: fully register-resident matvec (zero global traffic) ----
        float w00 = 0.f, w01 = 0.f, w10 = 0.f, w11 = 0.f;
        #pragma unroll
        for (int j4 = 0; j4 < NAGPR/4; ++j4) {       // rows 0..255 from AGPR
            const float4 z0 = zrow4[0][j4];
            const float4 z1 = zrow4[1][j4];
            float k0, k1, k2, k3;
            asm volatile("v_accvgpr_read_b32 %0, %1" : "=v"(k0) : "a"(ka[4*j4+0]));
            asm volatile("v_accvgpr_read_b32 %0, %1" : "=v"(k1) : "a"(ka[4*j4+1]));
            asm volatile("v_accvgpr_read_b32 %0, %1" : "=v"(k2) : "a"(ka[4*j4+2]));
            asm volatile("v_accvgpr_read_b32 %0, %1" : "=v"(k3) : "a"(ka[4*j4+3]));
            w00 = fmaf(k0, z0.x, w00); w01 = fmaf(k1, z0.y, w01);
            w00 = fmaf(k2, z0.z, w00); w01 = fmaf(k3, z0.w, w01);
            w10 = fmaf(k0, z1.x, w10); w11 = fmaf(k1, z1.y, w11);
            w10 = fmaf(k2, z1.z, w10); w11 = fmaf(k3, z1.w, w11);
        }
        #pragma unroll
        for (int j4 = 0; j4 < NVREG/4; ++j4) {       // rows 256..383 from VGPR
            const float4 z0 = zrow4[0][NAGPR/4 + j4];
            const float4 z1 = zrow4[1][NAGPR/4 + j4];
            w00 = fmaf(kk[4*j4+0], z0.x, w00); w01 = fmaf(kk[4*j4+1], z0.y, w01);
            w00 = fmaf(kk[4*j4+2], z0.z, w00); w01 = fmaf(kk[4*j4+3], z0.w, w01);
            w10 = fmaf(kk[4*j4+0], z1.x, w10); w11 = fmaf(kk[4*j4+1], z1.y, w11);
            w10 = fmaf(kk[4*j4+2], z1.z, w10); w11 = fmaf(kk[4*j4+3], z1.w, w11);
        }
        __syncthreads();   // B2 (zrow free; SD visible)

        // ---- phase 3: grad, clipped step, reg-ring, num partial ----
        const float wr[RPB] = { w00 + w01, w10 + w11 };
        float nump = 0.f;
        const int s = t & (RINGD - 1);
        #pragma unroll
        for (int r = 0; r < RPB; ++r) {
            float an = 0.f;
            if (vld[r]) {
                const float grad = SD[r] * (1.f - kb[r]) + 0.1f * z[r] + wr[r] - SD[2 + r] - 2.0f;
                an = z[r] - 0.001f * grad;
                an = fminf(fmaxf(an, 0.f), 1.f);
            }
            const float d = an - a[r];
            nump += d * d;
            #pragma unroll
            for (int s2 = 0; s2 < RINGD; ++s2) hist[s2][r] = (s2 == s) ? an : hist[s2][r];
            p[r] = a[r]; a[r] = an;
        }
        {
            float x = nump;
            x += __shfl_down(x, 32, 64); x += __shfl_down(x, 16, 64);
            x += __shfl_down(x,  8, 64); x += __shfl_down(x,  4, 64);
            x += __shfl_down(x,  2, 64); x += __shfl_down(x,  1, 64);
            if (lane == 0) rscr2[wv] = x;
        }
        __syncthreads();   // B3
        if (c == 0) {
            const float nb = rscr2[0] + rscr2[1] + rscr2[2] + rscr2[3] + rscr2[4] + rscr2[5];
            __hip_atomic_fetch_add(&num[t], nb, __ATOMIC_RELAXED, __HIP_MEMORY_SCOPE_AGENT);
            __hip_atomic_fetch_add(&den[t], SD[4], __ATOMIC_RELAXED, __HIP_MEMORY_SCOPE_AGENT);
            __hip_atomic_fetch_add(&arr[t], 1, __ATOMIC_RELEASE, __HIP_MEMORY_SCOPE_AGENT);
        }
    }

    // ---- finalize ----
    float av[RPB];
    #pragma unroll
    for (int r = 0; r < RPB; ++r) av[r] = a[r];
    if (stopT >= 0) {
        const int s = stopT & (RINGD - 1);
        #pragma unroll
        for (int s2 = 0; s2 < RINGD; ++s2)
            #pragma unroll
            for (int r = 0; r < RPB; ++r)
                av[r] = (s2 == s) ? hist[s2][r] : av[r];
    }
    #pragma unroll
    for (int r = 0; r < RPB; ++r) {
        if (vld[r]) {
            const int i = c - (c > bb[r] ? 1 : 0);
            afin[(size_t)bb[r] * BM1 + i] = av[r];
        }
    }
}

__global__ void __launch_bounds__(TPB)
loss_kernel(const float* __restrict__ Km, const float* __restrict__ afin,
            double* lossAcc) {
    const int b    = blockIdx.x;
    const int tid  = threadIdx.x;
    const int lane = tid & 63;
    const int wv   = tid >> 6;
    __shared__ double dscr[6][2];
    double np = 0.0, pp = 0.0;
    if (tid < BM1) {
        const float ay = afin[(size_t)b * BM1 + tid];
        const int   I  = tid + (tid >= b);
        np = (double)ay * (double)Km[(size_t)I * NZTOT + BSZ + b];
        pp = (double)ay * (double)Km[(size_t)b * NZTOT + BSZ + b];
    }
    for (int o = 32; o; o >>= 1) { np += __shfl_down(np, o, 64); pp += __shfl_down(pp, o, 64); }
    if (lane == 0) { dscr[wv][0] = np; dscr[wv][1] = pp; }
    __syncthreads();
    if (tid == 0) {
        double nb = 0.0, pb = 0.0;
        for (int w = 0; w < 6; ++w) { nb += dscr[w][0]; pb += dscr[w][1]; }
        __hip_atomic_fetch_add(&lossAcc[0], nb, __ATOMIC_RELAXED, __HIP_MEMORY_SCOPE_AGENT);
        __hip_atomic_fetch_add(&lossAcc[1], pb, __ATOMIC_RELAXED, __HIP_MEMORY_SCOPE_AGENT);
    }
}

__global__ void fin_kernel(const double* lossAcc, float* out) {
    out[0] = expf((float)(lossAcc[0] / 384.0 - lossAcc[1] / 384.0));
}

extern "C" void kernel_launch(void* const* d_in, const int* in_sizes, int n_in,
                              void* d_out, int out_size, void* d_ws, size_t ws_size,
                              hipStream_t stream) {
    const float* xis        = (const float*)d_in[0];
    const float* xjs        = (const float*)d_in[1];
    const float* alpha_init = (const float*)d_in[2];
    float* ws   = (float*)d_ws;
    float* Z    = ws + OFF_Z;
    float* nrm2 = ws + OFF_NRM;
    float* Km   = ws + OFF_K;
    float* KKp  = ws + OFF_KP;
    float* afin = ws + OFF_A;
    float* num  = ws + OFF_NUM;
    float* den  = ws + OFF_DEN;
    int*   arr  = (int*)(ws + OFF_ARR);
    double* lossAcc = (double*)(ws + OFF_LOSS);
    float* out  = (float*)d_out;

    hipLaunchKernelGGL(init_kernel, dim3(1), dim3(128), 0, stream, num, den, arr, lossAcc);
    hipLaunchKernelGGL(norm_kernel, dim3(NZTOT), dim3(64), 0, stream, xis, xjs, Z, nrm2);
    hipLaunchKernelGGL(k_kernel, dim3(BSZ, 3), dim3(256), 0, stream, Z, nrm2, Km, KKp);
    hipLaunchKernelGGL(pgd_kernel, dim3(NBLK), dim3(TPB), 0, stream,
                       Km, KKp, alpha_init, afin, num, den, arr);
    hipLaunchKernelGGL(loss_kernel, dim3(BSZ), dim3(TPB), 0, stream, Km, afin, lossAcc);
    hipLaunchKernelGGL(fin_kernel, dim3(1), dim3(1), 0, stream, lossAcc, out);
}

// Round 8
// 1182.721 us; speedup vs baseline: 36.3615x; 36.3615x over previous
//
#include <hip/hip_runtime.h>
#include <math.h>

#define BSZ   384
#define BM1   383
#define DIM   256
#define NZTOT 768
#define NBLK  192
#define RPB   2
#define TPB   384
#define NITER 100
#define RING  4
#define NVR   20               // K rows/quarter in VGPR (float4 each)
#define NLR   20               // K rows/quarter in LDS
#define KLDSB (4 * NLR * 384 * 4)   // 122880 B dynamic LDS

// ---- ws layout (float offsets) ----
#define OFF_Z    0          // 768*256
#define OFF_NRM  196608     // 768
#define OFF_K    197376     // 384*768
#define OFF_KP   492288     // 384*384 packed KK
#define OFF_A    639744     // 384*383 final alpha
#define OFF_NUM  786816     // NITER (pad 128)
#define OFF_DEN  786944
#define OFF_ARR  787072
#define OFF_LOSS 787200     // 2 doubles

__device__ __forceinline__ void fma4(float4& a, const float4 k, const float s) {
    a.x = fmaf(k.x, s, a.x); a.y = fmaf(k.y, s, a.y);
    a.z = fmaf(k.z, s, a.z); a.w = fmaf(k.w, s, a.w);
}

__global__ void init_kernel(float* num, float* den, int* arr, double* lossAcc) {
    int t = threadIdx.x;
    if (t < NITER) { num[t] = 0.f; den[t] = 0.f; arr[t] = 0; }
    if (t < 2) lossAcc[t] = 0.0;
}

__global__ void __launch_bounds__(64)
norm_kernel(const float* __restrict__ xis, const float* __restrict__ xjs,
            float* __restrict__ Z, float* __restrict__ nrm2) {
    const int row  = blockIdx.x;
    const int lane = threadIdx.x;
    const float* src = (row < BSZ) ? (xis + (size_t)row * DIM)
                                   : (xjs + (size_t)(row - BSZ) * DIM);
    float4 x = reinterpret_cast<const float4*>(src)[lane];
    float s = x.x*x.x + x.y*x.y + x.z*x.z + x.w*x.w;
    for (int m = 32; m; m >>= 1) s += __shfl_xor(s, m, 64);
    float nrm = sqrtf(s);
    float4 z;
    z.x = x.x / nrm; z.y = x.y / nrm; z.z = x.z / nrm; z.w = x.w / nrm;
    reinterpret_cast<float4*>(Z + (size_t)row * DIM)[lane] = z;
    float s2 = z.x*z.x + z.y*z.y + z.z*z.z + z.w*z.w;
    for (int m = 32; m; m >>= 1) s2 += __shfl_xor(s2, m, 64);
    if (lane == 0) nrm2[row] = s2;
}

__global__ void __launch_bounds__(256)
k_kernel(const float* __restrict__ Z, const float* __restrict__ nrm2,
         float* __restrict__ Km, float* __restrict__ KKp) {
    const int i = blockIdx.x;
    const int j = blockIdx.y * 256 + threadIdx.x;
    __shared__ float zi[DIM];
    zi[threadIdx.x] = Z[(size_t)i * DIM + threadIdx.x];
    __syncthreads();
    const float4* zr = reinterpret_cast<const float4*>(Z + (size_t)j * DIM);
    float acc = 0.f;
    #pragma unroll 8
    for (int k = 0; k < DIM/4; ++k) {
        float4 v = zr[k];
        acc = fmaf(zi[4*k+0], v.x, acc);
        acc = fmaf(zi[4*k+1], v.y, acc);
        acc = fmaf(zi[4*k+2], v.z, acc);
        acc = fmaf(zi[4*k+3], v.w, acc);
    }
    float sq = nrm2[i] + nrm2[j] - 2.f * acc;
    sq = fmaxf(sq, 0.f);
    const float val = expf(-0.1f * sq);
    Km[(size_t)i * NZTOT + j] = val;
    if (j < BSZ) KKp[(size_t)i * BSZ + j] = val;
}

// ---- streamed-batch macros (named regs, compile-time indices) ----
#define SLD8(S0,S1,S2,S3,S4,S5,S6,S7, RR) do {                               \
    S0 = KQ[(RR+0)*96]; S1 = KQ[(RR+1)*96]; S2 = KQ[(RR+2)*96];              \
    S3 = KQ[(RR+3)*96]; S4 = KQ[(RR+4)*96]; S5 = KQ[(RR+5)*96];              \
    S6 = KQ[(RR+6)*96]; S7 = KQ[(RR+7)*96]; } while (0)

#define SFMA8(S0,S1,S2,S3,S4,S5,S6,S7, J4R) do {                             \
    const float4 za0 = zrow4[0][zbase + (J4R)];                              \
    const float4 za1 = zrow4[1][zbase + (J4R)];                              \
    fma4(w0, S0, za0.x); fma4(w0, S1, za0.y);                                \
    fma4(w0, S2, za0.z); fma4(w0, S3, za0.w);                                \
    fma4(w1, S0, za1.x); fma4(w1, S1, za1.y);                                \
    fma4(w1, S2, za1.z); fma4(w1, S3, za1.w);                                \
    const float4 zb0 = zrow4[0][zbase + (J4R) + 1];                          \
    const float4 zb1 = zrow4[1][zbase + (J4R) + 1];                          \
    fma4(w0, S4, zb0.x); fma4(w0, S5, zb0.y);                                \
    fma4(w0, S6, zb0.z); fma4(w0, S7, zb0.w);                                \
    fma4(w1, S4, zb1.x); fma4(w1, S5, zb1.y);                                \
    fma4(w1, S6, zb1.z); fma4(w1, S7, zb1.w); } while (0)

__global__ void __launch_bounds__(TPB, 1)
pgd_kernel(const float* __restrict__ Km, const float* __restrict__ KKp,
           const float* __restrict__ alpha_init,
           float* __restrict__ afin, float* num, float* den, int* arr) {
    const int g    = blockIdx.x;     // 0..191
    const int c    = threadIdx.x;    // column 0..383 (phase 1/3 identity)
    const int lane = c & 63;
    const int wv   = c >> 6;
    const int q    = c / 96;         // quarter (phase 2)
    const int u    = c - q * 96;     // 0..95 -> output cols 4u..4u+3
    const int zbase = 24 * q;

    extern __shared__ float klds[];           // [4][NLR][384]

    __shared__ float4 zrow4[RPB][98];
    __shared__ float  wpart[4][RPB][BSZ];
    __shared__ float  ringb[RING][RPB][BSZ];
    __shared__ float  rscr[6][8];
    __shared__ float  rscr2[6];
    __shared__ float  SD[8];                  // 0..1 S_r, 2..3 D_r, 4 den
    __shared__ unsigned long long scanm[2];

    // ---- per-row init (diagonal thread c==b inert) ----
    float a[RPB], p[RPB], kb[RPB];
    int   bb[RPB]; bool vld[RPB];
    #pragma unroll
    for (int r = 0; r < RPB; ++r) {
        const int b = g * RPB + r;
        bb[r]  = b;
        vld[r] = (c != b);
        kb[r]  = Km[(size_t)b * NZTOT + c];
        float v = 0.f;
        if (vld[r]) {
            const int i = c - (c > b ? 1 : 0);
            v = alpha_init[(size_t)b * BM1 + i];
            v = fminf(fmaxf(v, 0.f), 1.f);
        }
        a[r] = v; p[r] = v;
    }

    // ---- prologue: resident K (VGPR rows 0..19, LDS rows 20..39 of quarter) ----
    const float4* __restrict__ KQ = reinterpret_cast<const float4*>(KKp)
                                    + (size_t)(96 * q) * 96 + u;
    float4 kv[NVR];
    #pragma unroll
    for (int m = 0; m < NVR; ++m) kv[m] = KQ[m * 96];
    #pragma unroll
    for (int row = 0; row < NLR; ++row)
        *reinterpret_cast<float4*>(&klds[((q * NLR) + row) * 384 + 4 * u]) = KQ[(NVR + row) * 96];
    __syncthreads();

    int stopT = -1;

    for (int t = 0; t < NITER; ++t) {
        // ---- phase 1: z build + S, D, den partials ----
        const float beta = (float)t / ((float)t + 3.0f);
        float z[RPB]; float vv[5]; float denp = 0.f;
        #pragma unroll
        for (int r = 0; r < RPB; ++r) {
            const float zr = a[r] + beta * (a[r] - p[r]);   // 0 on diagonal thread
            z[r] = zr;
            ((float*)&zrow4[r][0])[c] = zr;
            vv[r]     = zr;
            vv[2 + r] = kb[r] * zr;
            denp += a[r] * a[r];
        }
        vv[4] = denp;
        #pragma unroll
        for (int k = 0; k < 5; ++k) {
            float x = vv[k];
            x += __shfl_down(x, 32, 64); x += __shfl_down(x, 16, 64);
            x += __shfl_down(x,  8, 64); x += __shfl_down(x,  4, 64);
            x += __shfl_down(x,  2, 64); x += __shfl_down(x,  1, 64);
            if (lane == 0) rscr[wv][k] = x;
        }

        // ---- spin-free stop scan: thread tau checks iteration tau ----
        int ok = 0;
        if (c < NITER) {
            const int av = __hip_atomic_load(&arr[c], __ATOMIC_ACQUIRE, __HIP_MEMORY_SCOPE_AGENT);
            if (av == NBLK) {
                const float nn = __hip_atomic_load(&num[c], __ATOMIC_RELAXED, __HIP_MEMORY_SCOPE_AGENT);
                const float dd = __hip_atomic_load(&den[c], __ATOMIC_RELAXED, __HIP_MEMORY_SCOPE_AGENT);
                ok = (sqrtf(nn) / (sqrtf(dd) + 1e-8f) < 0.01f) ? 1 : 0;
            }
        }
        {
            const unsigned long long bm = __ballot(ok);
            if (lane == 0 && wv < 2) scanm[wv] = bm;
        }
        __syncthreads();   // B1
        {
            const unsigned long long m0 = scanm[0], m1 = scanm[1];
            const int st = m0 ? (__ffsll(m0) - 1) : (m1 ? 63 + __ffsll(m1) : -1);
            if (st >= 0) { stopT = st; break; }   // uniform across block
        }
        if (c < 5) {
            float s = 0.f;
            #pragma unroll
            for (int w = 0; w < 6; ++w) s += rscr[w][c];
            SD[c] = s;
        }

        // ---- phase 2: quarter matvec: VGPR(20) + LDS(20) + stream(56) rows ----
        float4 w0 = make_float4(0.f,0.f,0.f,0.f);
        float4 w1 = make_float4(0.f,0.f,0.f,0.f);
        {
            float4 sA0,sA1,sA2,sA3,sA4,sA5,sA6,sA7;
            float4 sB0,sB1,sB2,sB3,sB4,sB5,sB6,sB7;
            SLD8(sA0,sA1,sA2,sA3,sA4,sA5,sA6,sA7, 40);
            SLD8(sB0,sB1,sB2,sB3,sB4,sB5,sB6,sB7, 48);

            // VGPR-resident rows (j4rel 0..4)
            #pragma unroll
            for (int j4 = 0; j4 < 5; ++j4) {
                const float4 z0 = zrow4[0][zbase + j4];
                const float4 z1 = zrow4[1][zbase + j4];
                fma4(w0, kv[4*j4+0], z0.x); fma4(w0, kv[4*j4+1], z0.y);
                fma4(w0, kv[4*j4+2], z0.z); fma4(w0, kv[4*j4+3], z0.w);
                fma4(w1, kv[4*j4+0], z1.x); fma4(w1, kv[4*j4+1], z1.y);
                fma4(w1, kv[4*j4+2], z1.z); fma4(w1, kv[4*j4+3], z1.w);
            }

            SFMA8(sA0,sA1,sA2,sA3,sA4,sA5,sA6,sA7, 10);
            SLD8(sA0,sA1,sA2,sA3,sA4,sA5,sA6,sA7, 56);

            // LDS-resident rows (j4rel 5..9)
            #pragma unroll
            for (int j4 = 5; j4 < 10; ++j4) {
                const float4 z0 = zrow4[0][zbase + j4];
                const float4 z1 = zrow4[1][zbase + j4];
                const int row0 = (j4 - 5) * 4;
                const float4 k0 = *reinterpret_cast<const float4*>(&klds[((q*NLR)+row0+0)*384 + 4*u]);
                const float4 k1 = *reinterpret_cast<const float4*>(&klds[((q*NLR)+row0+1)*384 + 4*u]);
                const float4 k2 = *reinterpret_cast<const float4*>(&klds[((q*NLR)+row0+2)*384 + 4*u]);
                const float4 k3 = *reinterpret_cast<const float4*>(&klds[((q*NLR)+row0+3)*384 + 4*u]);
                fma4(w0, k0, z0.x); fma4(w0, k1, z0.y);
                fma4(w0, k2, z0.z); fma4(w0, k3, z0.w);
                fma4(w1, k0, z1.x); fma4(w1, k1, z1.y);
                fma4(w1, k2, z1.z); fma4(w1, k3, z1.w);
            }

            SFMA8(sB0,sB1,sB2,sB3,sB4,sB5,sB6,sB7, 12);
            SLD8(sB0,sB1,sB2,sB3,sB4,sB5,sB6,sB7, 64);
            SFMA8(sA0,sA1,sA2,sA3,sA4,sA5,sA6,sA7, 14);
            SLD8(sA0,sA1,sA2,sA3,sA4,sA5,sA6,sA7, 72);
            SFMA8(sB0,sB1,sB2,sB3,sB4,sB5,sB6,sB7, 16);
            SLD8(sB0,sB1,sB2,sB3,sB4,sB5,sB6,sB7, 80);
            SFMA8(sA0,sA1,sA2,sA3,sA4,sA5,sA6,sA7, 18);
            SLD8(sA0,sA1,sA2,sA3,sA4,sA5,sA6,sA7, 88);
            SFMA8(sB0,sB1,sB2,sB3,sB4,sB5,sB6,sB7, 20);
            SFMA8(sA0,sA1,sA2,sA3,sA4,sA5,sA6,sA7, 22);
        }
        *reinterpret_cast<float4*>(&wpart[q][0][4*u]) = w0;
        *reinterpret_cast<float4*>(&wpart[q][1][4*u]) = w1;
        __syncthreads();   // B2

        // ---- phase 3: grad, clipped step, LDS ring, num partial ----
        float nump = 0.f;
        #pragma unroll
        for (int r = 0; r < RPB; ++r) {
            const float w = (wpart[0][r][c] + wpart[1][r][c])
                          + (wpart[2][r][c] + wpart[3][r][c]);
            float an = 0.f;
            if (vld[r]) {
                const float grad = SD[r] * (1.f - kb[r]) + 0.1f * z[r] + w - SD[2 + r] - 2.0f;
                an = z[r] - 0.001f * grad;
                an = fminf(fmaxf(an, 0.f), 1.f);
            }
            ringb[t & (RING - 1)][r][c] = an;
            const float d = an - a[r];
            nump += d * d;
            p[r] = a[r]; a[r] = an;
        }
        {
            float x = nump;
            x += __shfl_down(x, 32, 64); x += __shfl_down(x, 16, 64);
            x += __shfl_down(x,  8, 64); x += __shfl_down(x,  4, 64);
            x += __shfl_down(x,  2, 64); x += __shfl_down(x,  1, 64);
            if (lane == 0) rscr2[wv] = x;
        }
        __syncthreads();   // B3
        if (c == 0) {
            const float nb = rscr2[0] + rscr2[1] + rscr2[2] + rscr2[3] + rscr2[4] + rscr2[5];
            __hip_atomic_fetch_add(&num[t], nb, __ATOMIC_RELAXED, __HIP_MEMORY_SCOPE_AGENT);
            __hip_atomic_fetch_add(&den[t], SD[4], __ATOMIC_RELAXED, __HIP_MEMORY_SCOPE_AGENT);
            __hip_atomic_fetch_add(&arr[t], 1, __ATOMIC_RELEASE, __HIP_MEMORY_SCOPE_AGENT);
        }
    }

    // ---- finalize (each thread reads its own ring slot; no barrier needed) ----
    #pragma unroll
    for (int r = 0; r < RPB; ++r) {
        if (vld[r]) {
            const float av = (stopT >= 0) ? ringb[stopT & (RING - 1)][r][c] : a[r];
            const int i = c - (c > bb[r] ? 1 : 0);
            afin[(size_t)bb[r] * BM1 + i] = av;
        }
    }
}

__global__ void __launch_bounds__(TPB)
loss_kernel(const float* __restrict__ Km, const float* __restrict__ afin,
            double* lossAcc) {
    const int b    = blockIdx.x;
    const int tid  = threadIdx.x;
    const int lane = tid & 63;
    const int wv   = tid >> 6;
    __shared__ double dscr[6][2];
    double np = 0.0, pp = 0.0;
    if (tid < BM1) {
        const float ay = afin[(size_t)b * BM1 + tid];
        const int   I  = tid + (tid >= b);
        np = (double)ay * (double)Km[(size_t)I * NZTOT + BSZ + b];
        pp = (double)ay * (double)Km[(size_t)b * NZTOT + BSZ + b];
    }
    for (int o = 32; o; o >>= 1) { np += __shfl_down(np, o, 64); pp += __shfl_down(pp, o, 64); }
    if (lane == 0) { dscr[wv][0] = np; dscr[wv][1] = pp; }
    __syncthreads();
    if (tid == 0) {
        double nb = 0.0, pb = 0.0;
        for (int w = 0; w < 6; ++w) { nb += dscr[w][0]; pb += dscr[w][1]; }
        __hip_atomic_fetch_add(&lossAcc[0], nb, __ATOMIC_RELAXED, __HIP_MEMORY_SCOPE_AGENT);
        __hip_atomic_fetch_add(&lossAcc[1], pb, __ATOMIC_RELAXED, __HIP_MEMORY_SCOPE_AGENT);
    }
}

__global__ void fin_kernel(const double* lossAcc, float* out) {
    out[0] = expf((float)(lossAcc[0] / 384.0 - lossAcc[1] / 384.0));
}

extern "C" void kernel_launch(void* const* d_in, const int* in_sizes, int n_in,
                              void* d_out, int out_size, void* d_ws, size_t ws_size,
                              hipStream_t stream) {
    const float* xis        = (const float*)d_in[0];
    const float* xjs        = (const float*)d_in[1];
    const float* alpha_init = (const float*)d_in[2];
    float* ws   = (float*)d_ws;
    float* Z    = ws + OFF_Z;
    float* nrm2 = ws + OFF_NRM;
    float* Km   = ws + OFF_K;
    float* KKp  = ws + OFF_KP;
    float* afin = ws + OFF_A;
    float* num  = ws + OFF_NUM;
    float* den  = ws + OFF_DEN;
    int*   arr  = (int*)(ws + OFF_ARR);
    double* lossAcc = (double*)(ws + OFF_LOSS);
    float* out  = (float*)d_out;

    hipFuncSetAttribute((const void*)pgd_kernel,
                        hipFuncAttributeMaxDynamicSharedMemorySize, KLDSB);

    hipLaunchKernelGGL(init_kernel, dim3(1), dim3(128), 0, stream, num, den, arr, lossAcc);
    hipLaunchKernelGGL(norm_kernel, dim3(NZTOT), dim3(64), 0, stream, xis, xjs, Z, nrm2);
    hipLaunchKernelGGL(k_kernel, dim3(BSZ, 3), dim3(256), 0, stream, Z, nrm2, Km, KKp);
    hipLaunchKernelGGL(pgd_kernel, dim3(NBLK), dim3(TPB), KLDSB, stream,
                       Km, KKp, alpha_init, afin, num, den, arr);
    hipLaunchKernelGGL(loss_kernel, dim3(BSZ), dim3(TPB), 0, stream, Km, afin, lossAcc);
    hipLaunchKernelGGL(fin_kernel, dim3(1), dim3(1), 0, stream, lossAcc, out);
}